// Round 1
// baseline (358.586 us; speedup 1.0000x reference)
//
#include <hip/hip_runtime.h>
#include <math.h>

// MS2D (VMamba SS2D) pipeline for MI355X.
// B=4, H=W=64, L=4096, DM=DI=96, N=16 states, K=4 directions, DTR=6.
// Chunked selective scan: NC=64 chunks of LC=64 steps.

#define LQ 4096
#define NCH 64   // chunks
#define LCH 64   // chunk length

__device__ __forceinline__ float sigmoid_f(float x){ return 1.0f/(1.0f + __expf(-x)); }
__device__ __forceinline__ float silu_f(float x){ return x * sigmoid_f(x); }
__device__ __forceinline__ float softplus_f(float x){ return (x > 20.0f) ? x : log1pf(__expf(x)); }

// scan-order index i -> spatial position p = h*64+w, for direction k
__device__ __forceinline__ int pos_of(int k, int i){
  switch(k & 3){
    case 0: return i;                                   // h,w raster
    case 1: return ((i & 63) << 6) | (i >> 6);          // w,h raster (transposed)
    case 2: return LQ - 1 - i;                          // reversed h,w
    default: { int j = LQ - 1 - i; return ((j & 63) << 6) | (j >> 6); }
  }
}

// ---------------- K1: in_proj GEMM: (16384 x 96) @ (96 x 192) -> xc | z ----
__global__ __launch_bounds__(256) void k_inproj(const float* __restrict__ x,
                                                const float* __restrict__ wproj,
                                                float* __restrict__ xc,
                                                float* __restrict__ zb){
  __shared__ float a_s[64*97];     // 64 rows x 96 (+1 pad)
  __shared__ float w_s[192*97];    // 192 rows x 96 (+1 pad)
  const int t = threadIdx.x;
  const int row0 = blockIdx.x * 64;
  for (int e = t*4; e < 64*96; e += 1024){
    float4 v = *(const float4*)(x + row0*96 + e);
    int r = e/96, c = e%96;
    float* p = a_s + r*97 + c;
    p[0]=v.x; p[1]=v.y; p[2]=v.z; p[3]=v.w;
  }
  for (int e = t*4; e < 192*96; e += 1024){
    float4 v = *(const float4*)(wproj + e);
    int r = e/96, c = e%96;
    float* p = w_s + r*97 + c;
    p[0]=v.x; p[1]=v.y; p[2]=v.z; p[3]=v.w;
  }
  __syncthreads();
  const int tr = t >> 5, tc = t & 31;   // micro-tile: 8 rows x 6 cols
  float acc[8][6];
  #pragma unroll
  for (int i=0;i<8;i++){
    #pragma unroll
    for (int j=0;j<6;j++) acc[i][j]=0.f;
  }
  for (int kk=0; kk<96; kk++){
    float a[8], b[6];
    #pragma unroll
    for (int i=0;i<8;i++) a[i] = a_s[(tr*8+i)*97+kk];
    #pragma unroll
    for (int j=0;j<6;j++) b[j] = w_s[(tc*6+j)*97+kk];
    #pragma unroll
    for (int i=0;i<8;i++){
      #pragma unroll
      for (int j=0;j<6;j++) acc[i][j] += a[i]*b[j];
    }
  }
  #pragma unroll
  for (int i=0;i<8;i++){
    int row = row0 + tr*8 + i;
    #pragma unroll
    for (int j=0;j<6;j++){
      int c = tc*6+j;
      float v = acc[i][j];
      if (c < 96) xc[row*96+c] = v;
      else        zb[row*96+(c-96)] = v;
    }
  }
}

// ---------------- K2: depthwise 3x3 conv (SAME) + bias + SiLU --------------
__global__ __launch_bounds__(256) void k_conv(const float* __restrict__ xc,
                                              const float* __restrict__ cw,
                                              const float* __restrict__ cb,
                                              float* __restrict__ u){
  int e = blockIdx.x*256 + threadIdx.x;      // < 4*4096*96
  int d = e % 96;
  int p = e / 96;
  int w = p & 63, h = (p >> 6) & 63, b = p >> 12;
  float acc = cb[d];
  #pragma unroll
  for (int kh=0; kh<3; kh++){
    int hh = h + kh - 1;
    if (hh < 0 || hh > 63) continue;
    #pragma unroll
    for (int kw=0; kw<3; kw++){
      int ww = w + kw - 1;
      if (ww < 0 || ww > 63) continue;
      acc += xc[(((b<<12) + (hh<<6) + ww))*96 + d] * cw[d*9 + kh*3 + kw];
    }
  }
  u[e] = silu_f(acc);
}

// ---------------- K3: x_proj: per (b,k,p): 38x96 GEMV -> dt_raw/Bs/Cs ------
__global__ __launch_bounds__(64) void k_proj(const float* __restrict__ u,
                                             const float* __restrict__ xpw,
                                             float* __restrict__ dts,
                                             float* __restrict__ Bsb,
                                             float* __restrict__ Csb){
  __shared__ float u_s[64*97];   // 64 positions x 96
  __shared__ float w_s[40*97];   // 38 (+2 zero pad) x 96
  const int t = threadIdx.x;
  const int blk = blockIdx.x;             // B*K*64 = 1024
  const int pt = blk & 63, k = (blk >> 6) & 3, b = blk >> 8;
  const int p0 = pt * 64;
  for (int e = t*4; e < 64*96; e += 256){
    int pp = e/96, c = e%96;
    float4 v = *(const float4*)(u + ((b<<12) + p0 + pp)*96 + c);
    float* p = u_s + pp*97 + c;
    p[0]=v.x; p[1]=v.y; p[2]=v.z; p[3]=v.w;
  }
  for (int e = t; e < 40*96; e += 64){
    int r = e/96, c = e%96;
    w_s[r*97+c] = (r < 38) ? xpw[(k*38+r)*96 + c] : 0.0f;
  }
  __syncthreads();
  const int posg = t >> 3, cg = t & 7;    // micro-tile 8 pos x 5 c
  float acc[8][5];
  #pragma unroll
  for (int i=0;i<8;i++){
    #pragma unroll
    for (int j=0;j<5;j++) acc[i][j]=0.f;
  }
  for (int dd=0; dd<96; dd++){
    float uu[8], wv[5];
    #pragma unroll
    for (int i=0;i<8;i++) uu[i] = u_s[(posg*8+i)*97+dd];
    #pragma unroll
    for (int j=0;j<5;j++) wv[j] = w_s[(cg*5+j)*97+dd];
    #pragma unroll
    for (int i=0;i<8;i++){
      #pragma unroll
      for (int j=0;j<5;j++) acc[i][j] += uu[i]*wv[j];
    }
  }
  #pragma unroll
  for (int i=0;i<8;i++){
    int p = p0 + posg*8 + i;
    int base = ((b*4+k)<<12) + p;
    #pragma unroll
    for (int j=0;j<5;j++){
      int c = cg*5 + j;
      float v = acc[i][j];
      if (c < 6)       dts[base*6 + c] = v;
      else if (c < 22) Bsb[base*16 + (c-6)] = v;
      else if (c < 38) Csb[base*16 + (c-22)] = v;
    }
  }
}

// ---------------- K4: scan phase A: per-chunk local scan from h=0 ----------
__global__ __launch_bounds__(128) void k_scanA(const float* __restrict__ u,
                                               const float* __restrict__ dts,
                                               const float* __restrict__ Bsb,
                                               const float* __restrict__ dtw_g,
                                               const float* __restrict__ dtb_g,
                                               const float* __restrict__ Alogs,
                                               float* __restrict__ S,
                                               float* __restrict__ sumd){
  const int d = threadIdx.x;
  if (d >= 96) return;                     // no barriers below
  const int blk = blockIdx.x;              // (b*4+k)*64 + chunk
  const int chunk = blk & 63, k = (blk >> 6) & 3, b = blk >> 8;
  const int bk = b*4 + k;
  float An[16];
  #pragma unroll
  for (int n=0;n<16;n++) An[n] = -__expf(Alogs[(k*96+d)*16+n]);
  float dtw[6];
  #pragma unroll
  for (int r=0;r<6;r++) dtw[r] = dtw_g[(k*96+d)*6+r];
  const float bias = dtb_g[k*96+d];
  float h[16];
  #pragma unroll
  for (int n=0;n<16;n++) h[n]=0.f;
  float sdelta = 0.f;
  for (int il=0; il<LCH; il++){
    const int i = chunk*LCH + il;
    const int p = pos_of(k, i);
    const float uv = u[((b<<12)+p)*96 + d];
    const float2* dr = (const float2*)(dts + ((bk<<12)+p)*6);
    float2 q0 = dr[0], q1 = dr[1], q2 = dr[2];
    float accd = bias + dtw[0]*q0.x + dtw[1]*q0.y + dtw[2]*q1.x
                      + dtw[3]*q1.y + dtw[4]*q2.x + dtw[5]*q2.y;
    float delta = softplus_f(accd);
    sdelta += delta;
    float du = delta * uv;
    const float4* Bp = (const float4*)(Bsb + ((bk<<12)+p)*16);
    float4 b0 = Bp[0], b1 = Bp[1], b2 = Bp[2], b3 = Bp[3];
    float Bv[16] = {b0.x,b0.y,b0.z,b0.w, b1.x,b1.y,b1.z,b1.w,
                    b2.x,b2.y,b2.z,b2.w, b3.x,b3.y,b3.z,b3.w};
    #pragma unroll
    for (int n=0;n<16;n++) h[n] = h[n]*__expf(delta*An[n]) + du*Bv[n];
  }
  float4* Sp = (float4*)(S + (blk*96 + d)*16);
  Sp[0] = make_float4(h[0],h[1],h[2],h[3]);
  Sp[1] = make_float4(h[4],h[5],h[6],h[7]);
  Sp[2] = make_float4(h[8],h[9],h[10],h[11]);
  Sp[3] = make_float4(h[12],h[13],h[14],h[15]);
  sumd[blk*96 + d] = sdelta;
}

// ---------------- K5: scan phase B: stitch chunk states --------------------
__global__ __launch_bounds__(256) void k_scanB(const float* __restrict__ S,
                                               const float* __restrict__ sumd,
                                               const float* __restrict__ Alogs,
                                               float* __restrict__ hinit){
  const int t = blockIdx.x*256 + threadIdx.x;  // < 16*96*16 = 24576
  const int n = t & 15;
  const int d = (t >> 4) % 96;
  const int bk = t / 1536;
  const int k = bk & 3;
  const float An = -__expf(Alogs[(k*96+d)*16+n]);
  float h = 0.f;
  for (int c=0;c<NCH;c++){
    const int sb = (bk*NCH + c)*96 + d;
    hinit[sb*16+n] = h;
    float P = __expf(An * sumd[sb]);
    h = h*P + S[sb*16+n];
  }
}

// ---------------- K6: scan phase C: re-run chunk with true h0, emit y ------
__global__ __launch_bounds__(128) void k_scanC(const float* __restrict__ u,
                                               const float* __restrict__ dts,
                                               const float* __restrict__ Bsb,
                                               const float* __restrict__ Csb,
                                               const float* __restrict__ dtw_g,
                                               const float* __restrict__ dtb_g,
                                               const float* __restrict__ Alogs,
                                               const float* __restrict__ Dsg,
                                               const float* __restrict__ hinit,
                                               float* __restrict__ ys){
  const int d = threadIdx.x;
  if (d >= 96) return;
  const int blk = blockIdx.x;
  const int chunk = blk & 63, k = (blk >> 6) & 3, b = blk >> 8;
  const int bk = b*4 + k;
  float An[16];
  #pragma unroll
  for (int n=0;n<16;n++) An[n] = -__expf(Alogs[(k*96+d)*16+n]);
  float dtw[6];
  #pragma unroll
  for (int r=0;r<6;r++) dtw[r] = dtw_g[(k*96+d)*6+r];
  const float bias = dtb_g[k*96+d];
  const float Dv = Dsg[k*96+d];
  float h[16];
  const float4* Hp = (const float4*)(hinit + (blk*96 + d)*16);
  {
    float4 h0=Hp[0], h1=Hp[1], h2=Hp[2], h3=Hp[3];
    h[0]=h0.x;h[1]=h0.y;h[2]=h0.z;h[3]=h0.w; h[4]=h1.x;h[5]=h1.y;h[6]=h1.z;h[7]=h1.w;
    h[8]=h2.x;h[9]=h2.y;h[10]=h2.z;h[11]=h2.w; h[12]=h3.x;h[13]=h3.y;h[14]=h3.z;h[15]=h3.w;
  }
  for (int il=0; il<LCH; il++){
    const int i = chunk*LCH + il;
    const int p = pos_of(k, i);
    const float uv = u[((b<<12)+p)*96 + d];
    const float2* dr = (const float2*)(dts + ((bk<<12)+p)*6);
    float2 q0 = dr[0], q1 = dr[1], q2 = dr[2];
    float accd = bias + dtw[0]*q0.x + dtw[1]*q0.y + dtw[2]*q1.x
                      + dtw[3]*q1.y + dtw[4]*q2.x + dtw[5]*q2.y;
    float delta = softplus_f(accd);
    float du = delta * uv;
    const float4* Bp = (const float4*)(Bsb + ((bk<<12)+p)*16);
    const float4* Cp = (const float4*)(Csb + ((bk<<12)+p)*16);
    float4 b0 = Bp[0], b1 = Bp[1], b2 = Bp[2], b3 = Bp[3];
    float4 c0 = Cp[0], c1 = Cp[1], c2 = Cp[2], c3 = Cp[3];
    float Bv[16] = {b0.x,b0.y,b0.z,b0.w, b1.x,b1.y,b1.z,b1.w,
                    b2.x,b2.y,b2.z,b2.w, b3.x,b3.y,b3.z,b3.w};
    float Cv[16] = {c0.x,c0.y,c0.z,c0.w, c1.x,c1.y,c1.z,c1.w,
                    c2.x,c2.y,c2.z,c2.w, c3.x,c3.y,c3.z,c3.w};
    float y = 0.f;
    #pragma unroll
    for (int n=0;n<16;n++){
      h[n] = h[n]*__expf(delta*An[n]) + du*Bv[n];
      y += h[n]*Cv[n];
    }
    y += Dv*uv;
    ys[((bk<<12)+p)*96 + d] = y;   // spatial write folds flip/transpose undo
  }
}

// ---------------- K7: sum 4 dirs + LayerNorm + z-gate + out_proj -----------
__global__ __launch_bounds__(256) void k_out(const float* __restrict__ ys,
                                             const float* __restrict__ zbuf,
                                             const float* __restrict__ nw,
                                             const float* __restrict__ nb,
                                             const float* __restrict__ wout,
                                             float* __restrict__ out){
  __shared__ float w_s[96*97];
  __shared__ float g_s[64*97];
  __shared__ float redA[256];
  __shared__ float redB[256];
  const int t = threadIdx.x;
  const int b = blockIdx.x >> 6;      // 256 blocks: b in 0..3, 64 pos tiles
  const int pt = blockIdx.x & 63;
  const int p0 = pt * 64;
  for (int e=t*4; e<96*96; e+=1024){
    float4 v = *(const float4*)(wout+e);
    int r=e/96, c=e%96;
    float* p = w_s + r*97 + c;
    p[0]=v.x; p[1]=v.y; p[2]=v.z; p[3]=v.w;
  }
  // phase 1: LN stats. thread -> (pos2 = t>>2, lane4 = t&3), 24 d each
  const int pos2 = t >> 2, lane4 = t & 3, d0 = lane4*24;
  const int p = p0 + pos2;
  float yv[24];
  float s1=0.f, s2=0.f;
  #pragma unroll
  for (int i=0;i<24;i+=4){
    float4 a = make_float4(0,0,0,0);
    #pragma unroll
    for (int kk=0;kk<4;kk++){
      float4 v = *(const float4*)(ys + (((b*4+kk)<<12) + p)*96 + d0 + i);
      a.x+=v.x; a.y+=v.y; a.z+=v.z; a.w+=v.w;
    }
    yv[i]=a.x; yv[i+1]=a.y; yv[i+2]=a.z; yv[i+3]=a.w;
    s1 += a.x+a.y+a.z+a.w;
    s2 += a.x*a.x + a.y*a.y + a.z*a.z + a.w*a.w;
  }
  redA[t]=s1; redB[t]=s2;
  __syncthreads();
  if (lane4 < 2){ redA[t]+=redA[t+2]; redB[t]+=redB[t+2]; }
  __syncthreads();
  if (lane4 < 1){ redA[t]+=redA[t+1]; redB[t]+=redB[t+1]; }
  __syncthreads();
  const float mu = redA[pos2*4] * (1.0f/96.0f);
  const float var = redB[pos2*4] * (1.0f/96.0f) - mu*mu;
  const float rstd = rsqrtf(var + 1e-5f);
  #pragma unroll
  for (int i=0;i<24;i+=4){
    float4 zv = *(const float4*)(zbuf + ((b<<12)+p)*96 + d0 + i);
    float zz[4] = {zv.x,zv.y,zv.z,zv.w};
    #pragma unroll
    for (int q=0;q<4;q++){
      int d = d0+i+q;
      float yn = (yv[i+q]-mu)*rstd*nw[d] + nb[d];
      g_s[pos2*97 + d] = yn * silu_f(zz[q]);
    }
  }
  __syncthreads();
  // phase 2: out GEMM. thread -> (posg = t>>5: 8 pos, mg = t&31: 3 m)
  const int posg = t >> 5, mg = t & 31;
  float acc[8][3];
  #pragma unroll
  for (int i=0;i<8;i++){
    #pragma unroll
    for (int j=0;j<3;j++) acc[i][j]=0.f;
  }
  for (int dd=0; dd<96; dd++){
    float g8[8], w3[3];
    #pragma unroll
    for (int i=0;i<8;i++) g8[i] = g_s[(posg*8+i)*97+dd];
    #pragma unroll
    for (int j=0;j<3;j++) w3[j] = w_s[(mg*3+j)*97+dd];
    #pragma unroll
    for (int i=0;i<8;i++){
      #pragma unroll
      for (int j=0;j<3;j++) acc[i][j] += g8[i]*w3[j];
    }
  }
  #pragma unroll
  for (int i=0;i<8;i++){
    int prow = p0 + posg*8 + i;
    #pragma unroll
    for (int j=0;j<3;j++){
      out[((b<<12)+prow)*96 + mg*3 + j] = acc[i][j];
    }
  }
}

extern "C" void kernel_launch(void* const* d_in, const int* in_sizes, int n_in,
                              void* d_out, int out_size, void* d_ws, size_t ws_size,
                              hipStream_t stream) {
  (void)in_sizes; (void)n_in; (void)out_size;
  const float* x   = (const float*)d_in[0];
  const float* ipw = (const float*)d_in[1];
  const float* cw  = (const float*)d_in[2];
  const float* cb  = (const float*)d_in[3];
  const float* xpw = (const float*)d_in[4];
  const float* dtw = (const float*)d_in[5];
  const float* dtb = (const float*)d_in[6];
  const float* alg = (const float*)d_in[7];
  const float* dsg = (const float*)d_in[8];
  const float* nw  = (const float*)d_in[9];
  const float* nb  = (const float*)d_in[10];
  const float* wo  = (const float*)d_in[11];
  float* out = (float*)d_out;

  // workspace layout (floats). total = 15,171,584 floats = 60.7 MB
  float* w = (float*)d_ws;
  size_t off = 0;
  float* z_b    = w + off; off += 1572864;             // (B,L,96) z gate
  float* u_b    = w + off; off += 1572864;             // (B,L,96) conv+silu
  float* dts_b  = w + off; off += 393216;              // (B,K,L,6)
  float* Bs_b   = w + off; off += 1048576;             // (B,K,L,16)
  float* Cs_b   = w + off; off += 1048576;             // (B,K,L,16)
  float* S_b    = w + off; off += 1572864;             // (B*K,NC,96,16)
  float* sumd_b = w + off; off += 98304;               // (B*K,NC,96)
  float* hin_b  = w + off; off += 1572864;             // (B*K,NC,96,16)
  float* ys_b   = w + off; off += 6291456;             // (B*K,L,96)
  float* xc_b   = ys_b;  // alias: xc is dead before ys is written (K2 < K6)
  (void)ws_size;

  k_inproj<<<256, 256, 0, stream>>>(x, ipw, xc_b, z_b);
  k_conv  <<<6144, 256, 0, stream>>>(xc_b, cw, cb, u_b);
  k_proj  <<<1024, 64, 0, stream>>>(u_b, xpw, dts_b, Bs_b, Cs_b);
  k_scanA <<<1024, 128, 0, stream>>>(u_b, dts_b, Bs_b, dtw, dtb, alg, S_b, sumd_b);
  k_scanB <<<96, 256, 0, stream>>>(S_b, sumd_b, alg, hin_b);
  k_scanC <<<1024, 128, 0, stream>>>(u_b, dts_b, Bs_b, Cs_b, dtw, dtb, alg, dsg, hin_b, ys_b);
  k_out   <<<256, 256, 0, stream>>>(ys_b, z_b, nw, nb, wo, out);
}

// Round 2
// 300.768 us; speedup vs baseline: 1.1922x; 1.1922x over previous
//
#include <hip/hip_runtime.h>
#include <math.h>

// MS2D (VMamba SS2D) pipeline for MI355X.
// B=4, H=W=64, L=4096, DM=DI=96, N=16 states, K=4 directions, DTR=6.
// Chunked selective scan: NCH=128 chunks of LCH=32 steps.
// Scan blocks: 192 threads = 2 chunks x 96 d (no idle lanes).

#define LQ 4096
#define NCH 128  // chunks
#define LCH 32   // chunk length

__device__ __forceinline__ float sigmoid_f(float x){ return 1.0f/(1.0f + __expf(-x)); }
__device__ __forceinline__ float silu_f(float x){ return x * sigmoid_f(x); }
__device__ __forceinline__ float softplus_f(float x){ return (x > 20.0f) ? x : log1pf(__expf(x)); }

// scan-order index i -> spatial position p = h*64+w, for direction k
__device__ __forceinline__ int pos_of(int k, int i){
  switch(k & 3){
    case 0: return i;                                   // h,w raster
    case 1: return ((i & 63) << 6) | (i >> 6);          // w,h raster (transposed)
    case 2: return LQ - 1 - i;                          // reversed h,w
    default: { int j = LQ - 1 - i; return ((j & 63) << 6) | (j >> 6); }
  }
}

// e[idx] = r^(idx+1), r = exp(-delta): 1 exp + 15 mul replaces 16 exps.
__device__ __forceinline__ void pow_chain(float r, float* e){
  e[0]=r;
  float r2=r*r;      e[1]=r2;
  e[2]=r2*r;
  float r4=r2*r2;    e[3]=r4;
  e[4]=r4*r;  e[5]=r4*r2;  e[6]=r4*e[2];
  float r8=r4*r4;    e[7]=r8;
  e[8]=r8*r;  e[9]=r8*r2;  e[10]=r8*e[2]; e[11]=r8*r4;
  e[12]=r8*e[4]; e[13]=r8*e[5]; e[14]=r8*e[6]; e[15]=r8*r8;
}

// ---------------- K1: in_proj GEMM: (16384 x 96) @ (96 x 192) -> xc | z ----
__global__ __launch_bounds__(256) void k_inproj(const float* __restrict__ x,
                                                const float* __restrict__ wproj,
                                                float* __restrict__ xc,
                                                float* __restrict__ zb){
  __shared__ float a_s[64*97];     // 64 rows x 96 (+1 pad)
  __shared__ float w_s[192*97];    // 192 rows x 96 (+1 pad)
  const int t = threadIdx.x;
  const int row0 = blockIdx.x * 64;
  for (int e = t*4; e < 64*96; e += 1024){
    float4 v = *(const float4*)(x + row0*96 + e);
    int r = e/96, c = e%96;
    float* p = a_s + r*97 + c;
    p[0]=v.x; p[1]=v.y; p[2]=v.z; p[3]=v.w;
  }
  for (int e = t*4; e < 192*96; e += 1024){
    float4 v = *(const float4*)(wproj + e);
    int r = e/96, c = e%96;
    float* p = w_s + r*97 + c;
    p[0]=v.x; p[1]=v.y; p[2]=v.z; p[3]=v.w;
  }
  __syncthreads();
  const int tr = t >> 5, tc = t & 31;   // micro-tile: 8 rows x 6 cols
  float acc[8][6];
  #pragma unroll
  for (int i=0;i<8;i++){
    #pragma unroll
    for (int j=0;j<6;j++) acc[i][j]=0.f;
  }
  for (int kk=0; kk<96; kk++){
    float a[8], b[6];
    #pragma unroll
    for (int i=0;i<8;i++) a[i] = a_s[(tr*8+i)*97+kk];
    #pragma unroll
    for (int j=0;j<6;j++) b[j] = w_s[(tc*6+j)*97+kk];
    #pragma unroll
    for (int i=0;i<8;i++){
      #pragma unroll
      for (int j=0;j<6;j++) acc[i][j] += a[i]*b[j];
    }
  }
  #pragma unroll
  for (int i=0;i<8;i++){
    int row = row0 + tr*8 + i;
    #pragma unroll
    for (int j=0;j<6;j++){
      int c = tc*6+j;
      float v = acc[i][j];
      if (c < 96) xc[row*96+c] = v;
      else        zb[row*96+(c-96)] = v;
    }
  }
}

// ---------------- K2: depthwise 3x3 conv (SAME) + bias + SiLU --------------
__global__ __launch_bounds__(256) void k_conv(const float* __restrict__ xc,
                                              const float* __restrict__ cw,
                                              const float* __restrict__ cb,
                                              float* __restrict__ u){
  int e = blockIdx.x*256 + threadIdx.x;      // < 4*4096*96
  int d = e % 96;
  int p = e / 96;
  int w = p & 63, h = (p >> 6) & 63, b = p >> 12;
  float acc = cb[d];
  #pragma unroll
  for (int kh=0; kh<3; kh++){
    int hh = h + kh - 1;
    if (hh < 0 || hh > 63) continue;
    #pragma unroll
    for (int kw=0; kw<3; kw++){
      int ww = w + kw - 1;
      if (ww < 0 || ww > 63) continue;
      acc += xc[(((b<<12) + (hh<<6) + ww))*96 + d] * cw[d*9 + kh*3 + kw];
    }
  }
  u[e] = silu_f(acc);
}

// ---------------- K3: x_proj: per (b,k,p): 38x96 GEMV -> dt_raw/Bs/Cs ------
__global__ __launch_bounds__(64) void k_proj(const float* __restrict__ u,
                                             const float* __restrict__ xpw,
                                             float* __restrict__ dts,
                                             float* __restrict__ Bsb,
                                             float* __restrict__ Csb){
  __shared__ float u_s[64*97];   // 64 positions x 96
  __shared__ float w_s[40*97];   // 38 (+2 zero pad) x 96
  const int t = threadIdx.x;
  const int blk = blockIdx.x;             // B*K*64 = 1024
  const int pt = blk & 63, k = (blk >> 6) & 3, b = blk >> 8;
  const int p0 = pt * 64;
  for (int e = t*4; e < 64*96; e += 256){
    int pp = e/96, c = e%96;
    float4 v = *(const float4*)(u + ((b<<12) + p0 + pp)*96 + c);
    float* p = u_s + pp*97 + c;
    p[0]=v.x; p[1]=v.y; p[2]=v.z; p[3]=v.w;
  }
  for (int e = t; e < 40*96; e += 64){
    int r = e/96, c = e%96;
    w_s[r*97+c] = (r < 38) ? xpw[(k*38+r)*96 + c] : 0.0f;
  }
  __syncthreads();
  const int posg = t >> 3, cg = t & 7;    // micro-tile 8 pos x 5 c
  float acc[8][5];
  #pragma unroll
  for (int i=0;i<8;i++){
    #pragma unroll
    for (int j=0;j<5;j++) acc[i][j]=0.f;
  }
  for (int dd=0; dd<96; dd++){
    float uu[8], wv[5];
    #pragma unroll
    for (int i=0;i<8;i++) uu[i] = u_s[(posg*8+i)*97+dd];
    #pragma unroll
    for (int j=0;j<5;j++) wv[j] = w_s[(cg*5+j)*97+dd];
    #pragma unroll
    for (int i=0;i<8;i++){
      #pragma unroll
      for (int j=0;j<5;j++) acc[i][j] += uu[i]*wv[j];
    }
  }
  #pragma unroll
  for (int i=0;i<8;i++){
    int p = p0 + posg*8 + i;
    int base = ((b*4+k)<<12) + p;
    #pragma unroll
    for (int j=0;j<5;j++){
      int c = cg*5 + j;
      float v = acc[i][j];
      if (c < 6)       dts[base*6 + c] = v;
      else if (c < 22) Bsb[base*16 + (c-6)] = v;
      else if (c < 38) Csb[base*16 + (c-22)] = v;
    }
  }
}

// ---------------- K4: scan phase A: per-chunk local scan from h=0 ----------
template<bool FAST>
__device__ __forceinline__ void scanA_loop(int b,int bk,int k,int chunk,int d,
    const float* __restrict__ u, const float* __restrict__ dts,
    const float* __restrict__ Bsb, const float* dtw, float bias,
    const float* An, float* h, float& sdelta){
  for (int il=0; il<LCH; il++){
    const int i = chunk*LCH + il;
    const int p = pos_of(k, i);
    const float uv = u[((b<<12)+p)*96 + d];
    const float2* dr = (const float2*)(dts + ((size_t)((bk<<12)+p))*6);
    float2 q0 = dr[0], q1 = dr[1], q2 = dr[2];
    float accd = bias + dtw[0]*q0.x + dtw[1]*q0.y + dtw[2]*q1.x
                      + dtw[3]*q1.y + dtw[4]*q2.x + dtw[5]*q2.y;
    float delta = softplus_f(accd);
    sdelta += delta;
    float du = delta * uv;
    const float4* Bp = (const float4*)(Bsb + ((size_t)((bk<<12)+p))*16);
    float4 b0 = Bp[0], b1 = Bp[1], b2 = Bp[2], b3 = Bp[3];
    float Bv[16] = {b0.x,b0.y,b0.z,b0.w, b1.x,b1.y,b1.z,b1.w,
                    b2.x,b2.y,b2.z,b2.w, b3.x,b3.y,b3.z,b3.w};
    float e[16];
    if (FAST){ pow_chain(__expf(-delta), e); }
    else {
      #pragma unroll
      for (int n=0;n<16;n++) e[n] = __expf(delta*An[n]);
    }
    #pragma unroll
    for (int n=0;n<16;n++) h[n] = h[n]*e[n] + du*Bv[n];
  }
}

__global__ __launch_bounds__(192) void k_scanA(const float* __restrict__ u,
                                               const float* __restrict__ dts,
                                               const float* __restrict__ Bsb,
                                               const float* __restrict__ dtw_g,
                                               const float* __restrict__ dtb_g,
                                               const float* __restrict__ Alogs,
                                               float* __restrict__ S,
                                               float* __restrict__ sumd){
  const int t = threadIdx.x;
  const int d = t % 96;
  const int c2 = t / 96;                   // 0 or 1
  const int blk = blockIdx.x;              // 16 bk x 64 = 1024
  const int bk = blk >> 6;
  const int k = bk & 3, b = bk >> 2;
  const int chunk = ((blk & 63) << 1) | c2;
  float An[16];
  bool fast = true;
  #pragma unroll
  for (int n=0;n<16;n++){
    An[n] = -__expf(Alogs[(k*96+d)*16+n]);
    fast = fast && (fabsf(An[n] + (float)(n+1)) < 1e-3f*(float)(n+1));
  }
  float dtw[6];
  #pragma unroll
  for (int r=0;r<6;r++) dtw[r] = dtw_g[(k*96+d)*6+r];
  const float bias = dtb_g[k*96+d];
  float h[16];
  #pragma unroll
  for (int n=0;n<16;n++) h[n]=0.f;
  float sdelta = 0.f;
  if (fast) scanA_loop<true >(b,bk,k,chunk,d,u,dts,Bsb,dtw,bias,An,h,sdelta);
  else      scanA_loop<false>(b,bk,k,chunk,d,u,dts,Bsb,dtw,bias,An,h,sdelta);
  const int sb = (bk*NCH + chunk)*96 + d;
  float4* Sp = (float4*)(S + (size_t)sb*16);
  Sp[0] = make_float4(h[0],h[1],h[2],h[3]);
  Sp[1] = make_float4(h[4],h[5],h[6],h[7]);
  Sp[2] = make_float4(h[8],h[9],h[10],h[11]);
  Sp[3] = make_float4(h[12],h[13],h[14],h[15]);
  sumd[sb] = sdelta;
}

// ---------------- K5: scan phase B: stitch chunk states --------------------
__global__ __launch_bounds__(256) void k_scanB(const float* __restrict__ S,
                                               const float* __restrict__ sumd,
                                               const float* __restrict__ Alogs,
                                               float* __restrict__ hinit){
  const int t = blockIdx.x*256 + threadIdx.x;  // < 16*96*16 = 24576
  const int n = t & 15;
  const int d = (t >> 4) % 96;
  const int bk = t / 1536;
  const int k = bk & 3;
  const float An = -__expf(Alogs[(k*96+d)*16+n]);
  float h = 0.f;
  for (int c=0;c<NCH;c++){
    const int sb = (bk*NCH + c)*96 + d;
    hinit[(size_t)sb*16+n] = h;
    float P = __expf(An * sumd[sb]);
    h = h*P + S[(size_t)sb*16+n];
  }
}

// ---------------- K6: scan phase C: re-run chunk with true h0, emit y ------
template<bool FAST>
__device__ __forceinline__ void scanC_loop(int b,int bk,int k,int chunk,int d,
    const float* __restrict__ u, const float* __restrict__ dts,
    const float* __restrict__ Bsb, const float* __restrict__ Csb,
    const float* dtw, float bias, const float* An, float* h,
    float* __restrict__ ys){
  for (int il=0; il<LCH; il++){
    const int i = chunk*LCH + il;
    const int p = pos_of(k, i);
    const float uv = u[((b<<12)+p)*96 + d];
    const float2* dr = (const float2*)(dts + ((size_t)((bk<<12)+p))*6);
    float2 q0 = dr[0], q1 = dr[1], q2 = dr[2];
    float accd = bias + dtw[0]*q0.x + dtw[1]*q0.y + dtw[2]*q1.x
                      + dtw[3]*q1.y + dtw[4]*q2.x + dtw[5]*q2.y;
    float delta = softplus_f(accd);
    float du = delta * uv;
    const float4* Bp = (const float4*)(Bsb + ((size_t)((bk<<12)+p))*16);
    const float4* Cp = (const float4*)(Csb + ((size_t)((bk<<12)+p))*16);
    float4 b0 = Bp[0], b1 = Bp[1], b2 = Bp[2], b3 = Bp[3];
    float4 c0 = Cp[0], c1 = Cp[1], c2 = Cp[2], c3 = Cp[3];
    float Bv[16] = {b0.x,b0.y,b0.z,b0.w, b1.x,b1.y,b1.z,b1.w,
                    b2.x,b2.y,b2.z,b2.w, b3.x,b3.y,b3.z,b3.w};
    float Cv[16] = {c0.x,c0.y,c0.z,c0.w, c1.x,c1.y,c1.z,c1.w,
                    c2.x,c2.y,c2.z,c2.w, c3.x,c3.y,c3.z,c3.w};
    float e[16];
    if (FAST){ pow_chain(__expf(-delta), e); }
    else {
      #pragma unroll
      for (int n=0;n<16;n++) e[n] = __expf(delta*An[n]);
    }
    float y = 0.f;
    #pragma unroll
    for (int n=0;n<16;n++){
      h[n] = h[n]*e[n] + du*Bv[n];
      y += h[n]*Cv[n];
    }
    ys[((size_t)((bk<<12)+p))*96 + d] = y;  // spatial write folds flip/transpose undo
  }
}

__global__ __launch_bounds__(192) void k_scanC(const float* __restrict__ u,
                                               const float* __restrict__ dts,
                                               const float* __restrict__ Bsb,
                                               const float* __restrict__ Csb,
                                               const float* __restrict__ dtw_g,
                                               const float* __restrict__ dtb_g,
                                               const float* __restrict__ Alogs,
                                               const float* __restrict__ hinit,
                                               float* __restrict__ ys){
  const int t = threadIdx.x;
  const int d = t % 96;
  const int c2 = t / 96;
  const int blk = blockIdx.x;
  const int bk = blk >> 6;
  const int k = bk & 3, b = bk >> 2;
  const int chunk = ((blk & 63) << 1) | c2;
  float An[16];
  bool fast = true;
  #pragma unroll
  for (int n=0;n<16;n++){
    An[n] = -__expf(Alogs[(k*96+d)*16+n]);
    fast = fast && (fabsf(An[n] + (float)(n+1)) < 1e-3f*(float)(n+1));
  }
  float dtw[6];
  #pragma unroll
  for (int r=0;r<6;r++) dtw[r] = dtw_g[(k*96+d)*6+r];
  const float bias = dtb_g[k*96+d];
  float h[16];
  const int sb = (bk*NCH + chunk)*96 + d;
  const float4* Hp = (const float4*)(hinit + (size_t)sb*16);
  {
    float4 h0=Hp[0], h1=Hp[1], h2=Hp[2], h3=Hp[3];
    h[0]=h0.x;h[1]=h0.y;h[2]=h0.z;h[3]=h0.w; h[4]=h1.x;h[5]=h1.y;h[6]=h1.z;h[7]=h1.w;
    h[8]=h2.x;h[9]=h2.y;h[10]=h2.z;h[11]=h2.w; h[12]=h3.x;h[13]=h3.y;h[14]=h3.z;h[15]=h3.w;
  }
  if (fast) scanC_loop<true >(b,bk,k,chunk,d,u,dts,Bsb,Csb,dtw,bias,An,h,ys);
  else      scanC_loop<false>(b,bk,k,chunk,d,u,dts,Bsb,Csb,dtw,bias,An,h,ys);
}

// ---------------- K7: sum 4 dirs + D*u + LayerNorm + z-gate + out_proj -----
__global__ __launch_bounds__(256) void k_out(const float* __restrict__ ys,
                                             const float* __restrict__ ubuf,
                                             const float* __restrict__ Dsg,
                                             const float* __restrict__ zbuf,
                                             const float* __restrict__ nw,
                                             const float* __restrict__ nb,
                                             const float* __restrict__ wout,
                                             float* __restrict__ out){
  __shared__ float w_s[96*97];
  __shared__ float g_s[64*97];
  __shared__ float redA[256];
  __shared__ float redB[256];
  const int t = threadIdx.x;
  const int b = blockIdx.x >> 6;      // 256 blocks: b in 0..3, 64 pos tiles
  const int pt = blockIdx.x & 63;
  const int p0 = pt * 64;
  for (int e=t*4; e<96*96; e+=1024){
    float4 v = *(const float4*)(wout+e);
    int r=e/96, c=e%96;
    float* p = w_s + r*97 + c;
    p[0]=v.x; p[1]=v.y; p[2]=v.z; p[3]=v.w;
  }
  // phase 1: LN stats. thread -> (pos2 = t>>2, lane4 = t&3), 24 d each
  const int pos2 = t >> 2, lane4 = t & 3, d0 = lane4*24;
  const int p = p0 + pos2;
  float yv[24];
  float s1=0.f, s2=0.f;
  #pragma unroll
  for (int i=0;i<24;i+=4){
    float4 a = make_float4(0,0,0,0);
    #pragma unroll
    for (int kk=0;kk<4;kk++){
      float4 v = *(const float4*)(ys + ((size_t)(((b*4+kk)<<12) + p))*96 + d0 + i);
      a.x+=v.x; a.y+=v.y; a.z+=v.z; a.w+=v.w;
    }
    // + (sum_k Ds[k,d]) * u[b,p,d]
    float4 uv = *(const float4*)(ubuf + ((size_t)((b<<12)+p))*96 + d0 + i);
    #pragma unroll
    for (int q=0;q<4;q++){
      int dd = d0+i+q;
      float sD = Dsg[dd] + Dsg[96+dd] + Dsg[192+dd] + Dsg[288+dd];
      float uq = (q==0)?uv.x:(q==1)?uv.y:(q==2)?uv.z:uv.w;
      float* aq = (q==0)?&a.x:(q==1)?&a.y:(q==2)?&a.z:&a.w;
      *aq += sD * uq;
    }
    yv[i]=a.x; yv[i+1]=a.y; yv[i+2]=a.z; yv[i+3]=a.w;
    s1 += a.x+a.y+a.z+a.w;
    s2 += a.x*a.x + a.y*a.y + a.z*a.z + a.w*a.w;
  }
  redA[t]=s1; redB[t]=s2;
  __syncthreads();
  if (lane4 < 2){ redA[t]+=redA[t+2]; redB[t]+=redB[t+2]; }
  __syncthreads();
  if (lane4 < 1){ redA[t]+=redA[t+1]; redB[t]+=redB[t+1]; }
  __syncthreads();
  const float mu = redA[pos2*4] * (1.0f/96.0f);
  const float var = redB[pos2*4] * (1.0f/96.0f) - mu*mu;
  const float rstd = rsqrtf(var + 1e-5f);
  #pragma unroll
  for (int i=0;i<24;i+=4){
    float4 zv = *(const float4*)(zbuf + ((size_t)((b<<12)+p))*96 + d0 + i);
    float zz[4] = {zv.x,zv.y,zv.z,zv.w};
    #pragma unroll
    for (int q=0;q<4;q++){
      int d = d0+i+q;
      float yn = (yv[i+q]-mu)*rstd*nw[d] + nb[d];
      g_s[pos2*97 + d] = yn * silu_f(zz[q]);
    }
  }
  __syncthreads();
  // phase 2: out GEMM. thread -> (posg = t>>5: 8 pos, mg = t&31: 3 m)
  const int posg = t >> 5, mg = t & 31;
  float acc[8][3];
  #pragma unroll
  for (int i=0;i<8;i++){
    #pragma unroll
    for (int j=0;j<3;j++) acc[i][j]=0.f;
  }
  for (int dd=0; dd<96; dd++){
    float g8[8], w3[3];
    #pragma unroll
    for (int i=0;i<8;i++) g8[i] = g_s[(posg*8+i)*97+dd];
    #pragma unroll
    for (int j=0;j<3;j++) w3[j] = w_s[(mg*3+j)*97+dd];
    #pragma unroll
    for (int i=0;i<8;i++){
      #pragma unroll
      for (int j=0;j<3;j++) acc[i][j] += g8[i]*w3[j];
    }
  }
  #pragma unroll
  for (int i=0;i<8;i++){
    int prow = p0 + posg*8 + i;
    #pragma unroll
    for (int j=0;j<3;j++){
      out[((size_t)((b<<12)+prow))*96 + mg*3 + j] = acc[i][j];
    }
  }
}

extern "C" void kernel_launch(void* const* d_in, const int* in_sizes, int n_in,
                              void* d_out, int out_size, void* d_ws, size_t ws_size,
                              hipStream_t stream) {
  (void)in_sizes; (void)n_in; (void)out_size; (void)ws_size;
  const float* x   = (const float*)d_in[0];
  const float* ipw = (const float*)d_in[1];
  const float* cw  = (const float*)d_in[2];
  const float* cb  = (const float*)d_in[3];
  const float* xpw = (const float*)d_in[4];
  const float* dtw = (const float*)d_in[5];
  const float* dtb = (const float*)d_in[6];
  const float* alg = (const float*)d_in[7];
  const float* dsg = (const float*)d_in[8];
  const float* nw  = (const float*)d_in[9];
  const float* nb  = (const float*)d_in[10];
  const float* wo  = (const float*)d_in[11];
  float* out = (float*)d_out;

  // workspace layout (floats), total = 15,073,280 floats = 60.3 MB
  // ys region (6.29M) is time-shared: [xc 1.57M | S 3.15M | sumd 0.20M | 1.37M]
  //   xc: dead after k_conv; S/sumd: dead after k_scanB; ys written in k_scanC.
  float* w = (float*)d_ws;
  size_t off = 0;
  float* z_b    = w + off; off += 1572864;             // (B,L,96) z gate
  float* u_b    = w + off; off += 1572864;             // (B,L,96) conv+silu
  float* dts_b  = w + off; off += 393216;              // (B,K,L,6)
  float* Bs_b   = w + off; off += 1048576;             // (B,K,L,16)
  float* Cs_b   = w + off; off += 1048576;             // (B,K,L,16)
  float* hin_b  = w + off; off += 3145728;             // (B*K,NCH,96,16)
  float* ys_b   = w + off; off += 6291456;             // (B*K,L,96)
  float* xc_b   = ys_b;                                // alias
  float* S_b    = ys_b + 1572864;                      // alias
  float* sumd_b = ys_b + 1572864 + 3145728;            // alias

  k_inproj<<<256, 256, 0, stream>>>(x, ipw, xc_b, z_b);
  k_conv  <<<6144, 256, 0, stream>>>(xc_b, cw, cb, u_b);
  k_proj  <<<1024, 64, 0, stream>>>(u_b, xpw, dts_b, Bs_b, Cs_b);
  k_scanA <<<1024, 192, 0, stream>>>(u_b, dts_b, Bs_b, dtw, dtb, alg, S_b, sumd_b);
  k_scanB <<<96, 256, 0, stream>>>(S_b, sumd_b, alg, hin_b);
  k_scanC <<<1024, 192, 0, stream>>>(u_b, dts_b, Bs_b, Cs_b, dtw, dtb, alg, hin_b, ys_b);
  k_out   <<<256, 256, 0, stream>>>(ys_b, u_b, dsg, z_b, nw, nb, wo, out);
}

// Round 4
// 273.869 us; speedup vs baseline: 1.3093x; 1.0982x over previous
//
#include <hip/hip_runtime.h>
#include <math.h>

// MS2D (VMamba SS2D) pipeline for MI355X.
// B=4, H=W=64, L=4096, DM=DI=96, N=16 states, K=4 directions, DTR=6.
// Chunked selective scan: NCH=128 chunks of LCH=32 steps.
// Scan blocks: 384 threads = 2 chunks x 96 d x 2 n-halves (8 states/lane).

#define LQ 4096
#define NCH 128  // chunks
#define LCH 32   // chunk length

__device__ __forceinline__ float sigmoid_f(float x){ return 1.0f/(1.0f + __expf(-x)); }
__device__ __forceinline__ float silu_f(float x){ return x * sigmoid_f(x); }
// fast softplus: __logf(1+e^x) (~4 inst) instead of libm log1pf (slow path).
__device__ __forceinline__ float softplus_f(float x){ return (x > 20.0f) ? x : __logf(1.0f + __expf(x)); }

// scan-order index i -> spatial position p = h*64+w, for direction k.
// Within an aligned 32-step chunk, p is AFFINE in i (chunk ranges never
// cross a 64-boundary), so callers hoist base+step out of the loop.
__device__ __forceinline__ int pos_of(int k, int i){
  switch(k & 3){
    case 0: return i;                                   // h,w raster
    case 1: return ((i & 63) << 6) | (i >> 6);          // w,h raster (transposed)
    case 2: return LQ - 1 - i;                          // reversed h,w
    default: { int j = LQ - 1 - i; return ((j & 63) << 6) | (j >> 6); }
  }
}

// ---------------- K1: in_proj GEMM: (16384 x 96) @ (96 x 192) -> xc | z ----
__global__ __launch_bounds__(256) void k_inproj(const float* __restrict__ x,
                                                const float* __restrict__ wproj,
                                                float* __restrict__ xc,
                                                float* __restrict__ zb){
  __shared__ float a_s[64*97];     // 64 rows x 96 (+1 pad)
  __shared__ float w_s[192*97];    // 192 rows x 96 (+1 pad)
  const int t = threadIdx.x;
  const int row0 = blockIdx.x * 64;
  for (int e = t*4; e < 64*96; e += 1024){
    float4 v = *(const float4*)(x + row0*96 + e);
    int r = e/96, c = e%96;
    float* p = a_s + r*97 + c;
    p[0]=v.x; p[1]=v.y; p[2]=v.z; p[3]=v.w;
  }
  for (int e = t*4; e < 192*96; e += 1024){
    float4 v = *(const float4*)(wproj + e);
    int r = e/96, c = e%96;
    float* p = w_s + r*97 + c;
    p[0]=v.x; p[1]=v.y; p[2]=v.z; p[3]=v.w;
  }
  __syncthreads();
  const int tr = t >> 5, tc = t & 31;   // micro-tile: 8 rows x 6 cols
  float acc[8][6];
  #pragma unroll
  for (int i=0;i<8;i++){
    #pragma unroll
    for (int j=0;j<6;j++) acc[i][j]=0.f;
  }
  for (int kk=0; kk<96; kk++){
    float a[8], b[6];
    #pragma unroll
    for (int i=0;i<8;i++) a[i] = a_s[(tr*8+i)*97+kk];
    #pragma unroll
    for (int j=0;j<6;j++) b[j] = w_s[(tc*6+j)*97+kk];
    #pragma unroll
    for (int i=0;i<8;i++){
      #pragma unroll
      for (int j=0;j<6;j++) acc[i][j] += a[i]*b[j];
    }
  }
  #pragma unroll
  for (int i=0;i<8;i++){
    int row = row0 + tr*8 + i;
    #pragma unroll
    for (int j=0;j<6;j++){
      int c = tc*6+j;
      float v = acc[i][j];
      if (c < 96) xc[row*96+c] = v;
      else        zb[row*96+(c-96)] = v;
    }
  }
}

// ---------------- K2: depthwise 3x3 conv (SAME) + bias + SiLU, float4 ------
__global__ __launch_bounds__(256) void k_conv(const float* __restrict__ xc,
                                              const float* __restrict__ cw,
                                              const float* __restrict__ cb,
                                              float* __restrict__ u){
  int e = blockIdx.x*256 + threadIdx.x;      // < 4*4096*24
  int d0 = (e % 24) * 4;
  int p = e / 24;                            // GLOBAL row: b*4096 + spatial
  int w = p & 63, h = (p >> 6) & 63, b = p >> 12;
  float cwv[4][9];
  #pragma unroll
  for (int q=0;q<4;q++){
    #pragma unroll
    for (int tp=0;tp<9;tp++) cwv[q][tp] = cw[(d0+q)*9+tp];
  }
  float4 acc = make_float4(cb[d0], cb[d0+1], cb[d0+2], cb[d0+3]);
  #pragma unroll
  for (int kh=0; kh<3; kh++){
    int hh = h + kh - 1;
    if (hh < 0 || hh > 63) continue;
    #pragma unroll
    for (int kw=0; kw<3; kw++){
      int ww = w + kw - 1;
      if (ww < 0 || ww > 63) continue;
      float4 v = *(const float4*)(xc + ((size_t)((b<<12) + (hh<<6) + ww))*96 + d0);
      int tp = kh*3+kw;
      acc.x += v.x*cwv[0][tp]; acc.y += v.y*cwv[1][tp];
      acc.z += v.z*cwv[2][tp]; acc.w += v.w*cwv[3][tp];
    }
  }
  float4 o = make_float4(silu_f(acc.x), silu_f(acc.y), silu_f(acc.z), silu_f(acc.w));
  // p already includes the batch offset — do NOT add (b<<12) again (round-3 bug).
  *(float4*)(u + (size_t)p*96 + d0) = o;
}

// ---------------- K3: x_proj: per (b,k,ptile): 38x96 x 64pos -> dt/B/C -----
__global__ __launch_bounds__(128) void k_proj(const float* __restrict__ u,
                                              const float* __restrict__ xpw,
                                              float* __restrict__ dts,
                                              float* __restrict__ Bsb,
                                              float* __restrict__ Csb){
  __shared__ float u_s[64*97];   // 64 positions x 96
  __shared__ float w_s[40*97];   // 38 (+2 zero pad) x 96
  const int t = threadIdx.x;
  const int blk = blockIdx.x;             // B*K*64 = 1024
  const int pt = blk & 63, k = (blk >> 6) & 3, b = blk >> 8;
  const int p0 = pt * 64;
  for (int e = t*4; e < 64*96; e += 512){
    int pp = e/96, c = e%96;
    float4 v = *(const float4*)(u + ((size_t)((b<<12) + p0 + pp))*96 + c);
    float* p = u_s + pp*97 + c;
    p[0]=v.x; p[1]=v.y; p[2]=v.z; p[3]=v.w;
  }
  for (int e = t*4; e < 40*96; e += 512){
    int r = e/96, c = e%96;
    float4 v = (r < 38) ? *(const float4*)(xpw + (k*38+r)*96 + c)
                        : make_float4(0,0,0,0);
    float* p = w_s + r*97 + c;
    p[0]=v.x; p[1]=v.y; p[2]=v.z; p[3]=v.w;
  }
  __syncthreads();
  const int posg = t & 15, cg = t >> 4;    // micro-tile 4 pos x 5 c
  float acc[4][5];
  #pragma unroll
  for (int i=0;i<4;i++){
    #pragma unroll
    for (int j=0;j<5;j++) acc[i][j]=0.f;
  }
  for (int dd=0; dd<96; dd++){
    float uu[4], wv[5];
    #pragma unroll
    for (int i=0;i<4;i++) uu[i] = u_s[(posg*4+i)*97+dd];
    #pragma unroll
    for (int j=0;j<5;j++) wv[j] = w_s[(cg*5+j)*97+dd];
    #pragma unroll
    for (int i=0;i<4;i++){
      #pragma unroll
      for (int j=0;j<5;j++) acc[i][j] += uu[i]*wv[j];
    }
  }
  #pragma unroll
  for (int i=0;i<4;i++){
    int p = p0 + posg*4 + i;
    int base = ((b*4+k)<<12) + p;
    #pragma unroll
    for (int j=0;j<5;j++){
      int c = cg*5 + j;
      float v = acc[i][j];
      if (c < 6)       dts[(size_t)base*6 + c] = v;
      else if (c < 22) Bsb[(size_t)base*16 + (c-6)] = v;
      else if (c < 38) Csb[(size_t)base*16 + (c-22)] = v;
    }
  }
}

// half-powchain: e[j] = r^(j+1) for j<8, then scaled by r^8 if nh==1.
__device__ __forceinline__ void pow8(float r, int nh, float* e){
  e[0]=r;
  e[1]=r*r;
  e[2]=e[1]*r;
  e[3]=e[1]*e[1];
  e[4]=e[3]*r;
  e[5]=e[3]*e[1];
  e[6]=e[3]*e[2];
  e[7]=e[3]*e[3];
  float m = nh ? e[7] : 1.0f;
  #pragma unroll
  for (int j=0;j<8;j++) e[j] *= m;
}

// ---------------- K4: scan phase A: per-chunk local scan from h=0 ----------
template<bool FAST>
__device__ __forceinline__ void scanA_loop(const float* up, const float2* dtp,
    const float4* Bp, long ustep, long dtstep, long bstep,
    const float* dtw, float bias, int nh, const float* An, float* h, float& sdelta){
  #pragma unroll 4
  for (int il=0; il<LCH; il++){
    const float uv = *up;
    float2 q0 = dtp[0], q1 = dtp[1], q2 = dtp[2];
    float accd = bias + dtw[0]*q0.x + dtw[1]*q0.y + dtw[2]*q1.x
                      + dtw[3]*q1.y + dtw[4]*q2.x + dtw[5]*q2.y;
    float delta = softplus_f(accd);
    sdelta += delta;
    float du = delta * uv;
    float4 b0 = Bp[0], b1 = Bp[1];
    float Bv[8] = {b0.x,b0.y,b0.z,b0.w, b1.x,b1.y,b1.z,b1.w};
    float e[8];
    if (FAST){ pow8(__expf(-delta), nh, e); }
    else {
      #pragma unroll
      for (int n=0;n<8;n++) e[n] = __expf(delta*An[n]);
    }
    #pragma unroll
    for (int n=0;n<8;n++) h[n] = h[n]*e[n] + du*Bv[n];
    up += ustep; dtp += dtstep; Bp += bstep;
  }
}

__global__ __launch_bounds__(384) void k_scanA(const float* __restrict__ u,
                                               const float* __restrict__ dts,
                                               const float* __restrict__ Bsb,
                                               const float* __restrict__ dtw_g,
                                               const float* __restrict__ dtb_g,
                                               const float* __restrict__ Alogs,
                                               float* __restrict__ S,
                                               float* __restrict__ sumd){
  const int t = threadIdx.x;
  const int c2 = t / 192;
  const int lane = t & 63;
  const int wv3 = (t % 192) >> 6;          // 0..2
  const int nh = (lane >> 5) & 1;          // n-half
  const int d = wv3*32 + (lane & 31);
  const int blk = blockIdx.x;              // 16 bk x 64
  const int bk = blk >> 6;
  const int k = bk & 3, b = bk >> 2;
  const int chunk = ((blk & 63) << 1) | c2;
  float An[8];
  bool fast = true;
  #pragma unroll
  for (int j=0;j<8;j++){
    int n = nh*8 + j;
    An[j] = -__expf(Alogs[(k*96+d)*16+n]);
    fast = fast && (fabsf(An[j] + (float)(n+1)) < 1e-3f*(float)(n+1));
  }
  int wfast = __all(fast ? 1 : 0);
  float dtw[6];
  #pragma unroll
  for (int r=0;r<6;r++) dtw[r] = dtw_g[(k*96+d)*6+r];
  const float bias = dtb_g[k*96+d];
  // affine position within chunk
  const int i0 = chunk*LCH;
  const int pb = pos_of(k, i0);
  const int pstep = pos_of(k, i0+1) - pb;
  const float* up = u + ((size_t)((b<<12)+pb))*96 + d;
  const float2* dtp = (const float2*)(dts + ((size_t)((bk<<12)+pb))*6);
  const float4* Bp = (const float4*)(Bsb + ((size_t)((bk<<12)+pb))*16) + nh*2;
  const long ustep = (long)pstep*96;
  const long dtstep = (long)pstep*3;
  const long bstep = (long)pstep*4;
  float h[8];
  #pragma unroll
  for (int n=0;n<8;n++) h[n]=0.f;
  float sdelta = 0.f;
  if (wfast) scanA_loop<true >(up,dtp,Bp,ustep,dtstep,bstep,dtw,bias,nh,An,h,sdelta);
  else       scanA_loop<false>(up,dtp,Bp,ustep,dtstep,bstep,dtw,bias,nh,An,h,sdelta);
  const int sb = (bk*NCH + chunk)*96 + d;
  float4* Sp = (float4*)(S + (size_t)sb*16 + nh*8);
  Sp[0] = make_float4(h[0],h[1],h[2],h[3]);
  Sp[1] = make_float4(h[4],h[5],h[6],h[7]);
  if (nh == 0) sumd[sb] = sdelta;
}

// ---------------- K5: scan phase B: stitch chunk states --------------------
__global__ __launch_bounds__(256) void k_scanB(const float* __restrict__ S,
                                               const float* __restrict__ sumd,
                                               const float* __restrict__ Alogs,
                                               float* __restrict__ hinit){
  const int t = blockIdx.x*256 + threadIdx.x;  // < 16*96*16 = 24576
  const int n = t & 15;
  const int d = (t >> 4) % 96;
  const int bk = t / 1536;
  const int k = bk & 3;
  const float An = -__expf(Alogs[(k*96+d)*16+n]);
  float h = 0.f;
  for (int c=0;c<NCH;c++){
    const int sb = (bk*NCH + c)*96 + d;
    hinit[(size_t)sb*16+n] = h;
    float P = __expf(An * sumd[sb]);
    h = h*P + S[(size_t)sb*16+n];
  }
}

// ---------------- K6: scan phase C: re-run chunk with true h0, emit y ------
template<bool FAST>
__device__ __forceinline__ void scanC_loop(const float* up, const float2* dtp,
    const float4* Bp, const float4* Cp, float* yp,
    long ustep, long dtstep, long bstep,
    const float* dtw, float bias, int nh, const float* An, float* h){
  #pragma unroll 4
  for (int il=0; il<LCH; il++){
    const float uv = *up;
    float2 q0 = dtp[0], q1 = dtp[1], q2 = dtp[2];
    float accd = bias + dtw[0]*q0.x + dtw[1]*q0.y + dtw[2]*q1.x
                      + dtw[3]*q1.y + dtw[4]*q2.x + dtw[5]*q2.y;
    float delta = softplus_f(accd);
    float du = delta * uv;
    float4 b0 = Bp[0], b1 = Bp[1];
    float4 c0 = Cp[0], c1 = Cp[1];
    float Bv[8] = {b0.x,b0.y,b0.z,b0.w, b1.x,b1.y,b1.z,b1.w};
    float Cv[8] = {c0.x,c0.y,c0.z,c0.w, c1.x,c1.y,c1.z,c1.w};
    float e[8];
    if (FAST){ pow8(__expf(-delta), nh, e); }
    else {
      #pragma unroll
      for (int n=0;n<8;n++) e[n] = __expf(delta*An[n]);
    }
    float y8 = 0.f;
    #pragma unroll
    for (int n=0;n<8;n++){
      h[n] = h[n]*e[n] + du*Bv[n];
      y8 += h[n]*Cv[n];
    }
    float y = y8 + __shfl_xor(y8, 32, 64);
    if (nh == 0) *yp = y;
    up += ustep; dtp += dtstep; Bp += bstep; Cp += bstep; yp += ustep;
  }
}

__global__ __launch_bounds__(384) void k_scanC(const float* __restrict__ u,
                                               const float* __restrict__ dts,
                                               const float* __restrict__ Bsb,
                                               const float* __restrict__ Csb,
                                               const float* __restrict__ dtw_g,
                                               const float* __restrict__ dtb_g,
                                               const float* __restrict__ Alogs,
                                               const float* __restrict__ hinit,
                                               float* __restrict__ ys){
  const int t = threadIdx.x;
  const int c2 = t / 192;
  const int lane = t & 63;
  const int wv3 = (t % 192) >> 6;
  const int nh = (lane >> 5) & 1;
  const int d = wv3*32 + (lane & 31);
  const int blk = blockIdx.x;
  const int bk = blk >> 6;
  const int k = bk & 3, b = bk >> 2;
  const int chunk = ((blk & 63) << 1) | c2;
  float An[8];
  bool fast = true;
  #pragma unroll
  for (int j=0;j<8;j++){
    int n = nh*8 + j;
    An[j] = -__expf(Alogs[(k*96+d)*16+n]);
    fast = fast && (fabsf(An[j] + (float)(n+1)) < 1e-3f*(float)(n+1));
  }
  int wfast = __all(fast ? 1 : 0);
  float dtw[6];
  #pragma unroll
  for (int r=0;r<6;r++) dtw[r] = dtw_g[(k*96+d)*6+r];
  const float bias = dtb_g[k*96+d];
  const int i0 = chunk*LCH;
  const int pb = pos_of(k, i0);
  const int pstep = pos_of(k, i0+1) - pb;
  const float* up = u + ((size_t)((b<<12)+pb))*96 + d;
  const float2* dtp = (const float2*)(dts + ((size_t)((bk<<12)+pb))*6);
  const float4* Bp = (const float4*)(Bsb + ((size_t)((bk<<12)+pb))*16) + nh*2;
  const float4* Cp = (const float4*)(Csb + ((size_t)((bk<<12)+pb))*16) + nh*2;
  float* yp = ys + ((size_t)((bk<<12)+pb))*96 + d;
  const long ustep = (long)pstep*96;
  const long dtstep = (long)pstep*3;
  const long bstep = (long)pstep*4;
  float h[8];
  const int sb = (bk*NCH + chunk)*96 + d;
  const float4* Hp = (const float4*)(hinit + (size_t)sb*16 + nh*8);
  {
    float4 h0=Hp[0], h1=Hp[1];
    h[0]=h0.x;h[1]=h0.y;h[2]=h0.z;h[3]=h0.w;
    h[4]=h1.x;h[5]=h1.y;h[6]=h1.z;h[7]=h1.w;
  }
  if (wfast) scanC_loop<true >(up,dtp,Bp,Cp,yp,ustep,dtstep,bstep,dtw,bias,nh,An,h);
  else       scanC_loop<false>(up,dtp,Bp,Cp,yp,ustep,dtstep,bstep,dtw,bias,nh,An,h);
}

// ---------------- K7: sum 4 dirs + D*u + LayerNorm + z-gate + out_proj -----
__global__ __launch_bounds__(256) void k_out(const float* __restrict__ ys,
                                             const float* __restrict__ ubuf,
                                             const float* __restrict__ Dsg,
                                             const float* __restrict__ zbuf,
                                             const float* __restrict__ nw,
                                             const float* __restrict__ nb,
                                             const float* __restrict__ wout,
                                             float* __restrict__ out){
  __shared__ float w_s[96*97];
  __shared__ float g_s[64*97];
  __shared__ float redA[256];
  __shared__ float redB[256];
  const int t = threadIdx.x;
  const int b = blockIdx.x >> 6;      // 256 blocks: b in 0..3, 64 pos tiles
  const int pt = blockIdx.x & 63;
  const int p0 = pt * 64;
  for (int e=t*4; e<96*96; e+=1024){
    float4 v = *(const float4*)(wout+e);
    int r=e/96, c=e%96;
    float* p = w_s + r*97 + c;
    p[0]=v.x; p[1]=v.y; p[2]=v.z; p[3]=v.w;
  }
  // phase 1: LN stats. thread -> (pos2 = t>>2, lane4 = t&3), 24 d each
  const int pos2 = t >> 2, lane4 = t & 3, d0 = lane4*24;
  const int p = p0 + pos2;
  float yv[24];
  float s1=0.f, s2=0.f;
  #pragma unroll
  for (int i=0;i<24;i+=4){
    float4 a = make_float4(0,0,0,0);
    #pragma unroll
    for (int kk=0;kk<4;kk++){
      float4 v = *(const float4*)(ys + ((size_t)(((b*4+kk)<<12) + p))*96 + d0 + i);
      a.x+=v.x; a.y+=v.y; a.z+=v.z; a.w+=v.w;
    }
    // + (sum_k Ds[k,d]) * u[b,p,d]
    float4 uv = *(const float4*)(ubuf + ((size_t)((b<<12)+p))*96 + d0 + i);
    #pragma unroll
    for (int q=0;q<4;q++){
      int dd = d0+i+q;
      float sD = Dsg[dd] + Dsg[96+dd] + Dsg[192+dd] + Dsg[288+dd];
      float uq = (q==0)?uv.x:(q==1)?uv.y:(q==2)?uv.z:uv.w;
      float* aq = (q==0)?&a.x:(q==1)?&a.y:(q==2)?&a.z:&a.w;
      *aq += sD * uq;
    }
    yv[i]=a.x; yv[i+1]=a.y; yv[i+2]=a.z; yv[i+3]=a.w;
    s1 += a.x+a.y+a.z+a.w;
    s2 += a.x*a.x + a.y*a.y + a.z*a.z + a.w*a.w;
  }
  redA[t]=s1; redB[t]=s2;
  __syncthreads();
  if (lane4 < 2){ redA[t]+=redA[t+2]; redB[t]+=redB[t+2]; }
  __syncthreads();
  if (lane4 < 1){ redA[t]+=redA[t+1]; redB[t]+=redB[t+1]; }
  __syncthreads();
  const float mu = redA[pos2*4] * (1.0f/96.0f);
  const float var = redB[pos2*4] * (1.0f/96.0f) - mu*mu;
  const float rstd = rsqrtf(var + 1e-5f);
  #pragma unroll
  for (int i=0;i<24;i+=4){
    float4 zv = *(const float4*)(zbuf + ((size_t)((b<<12)+p))*96 + d0 + i);
    float zz[4] = {zv.x,zv.y,zv.z,zv.w};
    #pragma unroll
    for (int q=0;q<4;q++){
      int d = d0+i+q;
      float yn = (yv[i+q]-mu)*rstd*nw[d] + nb[d];
      g_s[pos2*97 + d] = yn * silu_f(zz[q]);
    }
  }
  __syncthreads();
  // phase 2: out GEMM. thread -> (posg = t>>5: 8 pos, mg = t&31: 3 m)
  const int posg = t >> 5, mg = t & 31;
  float acc[8][3];
  #pragma unroll
  for (int i=0;i<8;i++){
    #pragma unroll
    for (int j=0;j<3;j++) acc[i][j]=0.f;
  }
  for (int dd=0; dd<96; dd++){
    float g8[8], w3[3];
    #pragma unroll
    for (int i=0;i<8;i++) g8[i] = g_s[(posg*8+i)*97+dd];
    #pragma unroll
    for (int j=0;j<3;j++) w3[j] = w_s[(mg*3+j)*97+dd];
    #pragma unroll
    for (int i=0;i<8;i++){
      #pragma unroll
      for (int j=0;j<3;j++) acc[i][j] += g8[i]*w3[j];
    }
  }
  #pragma unroll
  for (int i=0;i<8;i++){
    int prow = p0 + posg*8 + i;
    #pragma unroll
    for (int j=0;j<3;j++){
      out[((size_t)((b<<12)+prow))*96 + mg*3 + j] = acc[i][j];
    }
  }
}

extern "C" void kernel_launch(void* const* d_in, const int* in_sizes, int n_in,
                              void* d_out, int out_size, void* d_ws, size_t ws_size,
                              hipStream_t stream) {
  (void)in_sizes; (void)n_in; (void)out_size; (void)ws_size;
  const float* x   = (const float*)d_in[0];
  const float* ipw = (const float*)d_in[1];
  const float* cw  = (const float*)d_in[2];
  const float* cb  = (const float*)d_in[3];
  const float* xpw = (const float*)d_in[4];
  const float* dtw = (const float*)d_in[5];
  const float* dtb = (const float*)d_in[6];
  const float* alg = (const float*)d_in[7];
  const float* dsg = (const float*)d_in[8];
  const float* nw  = (const float*)d_in[9];
  const float* nb  = (const float*)d_in[10];
  const float* wo  = (const float*)d_in[11];
  float* out = (float*)d_out;

  // workspace layout (floats), total = 15,073,280 floats = 60.3 MB
  // ys region (6.29M) is time-shared: [xc 1.57M | S 3.15M | sumd 0.20M | 1.37M]
  //   xc: dead after k_conv; S/sumd: dead after k_scanB; ys written in k_scanC.
  float* w = (float*)d_ws;
  size_t off = 0;
  float* z_b    = w + off; off += 1572864;             // (B,L,96) z gate
  float* u_b    = w + off; off += 1572864;             // (B,L,96) conv+silu
  float* dts_b  = w + off; off += 393216;              // (B,K,L,6)
  float* Bs_b   = w + off; off += 1048576;             // (B,K,L,16)
  float* Cs_b   = w + off; off += 1048576;             // (B,K,L,16)
  float* hin_b  = w + off; off += 3145728;             // (B*K,NCH,96,16)
  float* ys_b   = w + off; off += 6291456;             // (B*K,L,96)
  float* xc_b   = ys_b;                                // alias
  float* S_b    = ys_b + 1572864;                      // alias
  float* sumd_b = ys_b + 1572864 + 3145728;            // alias

  k_inproj<<<256, 256, 0, stream>>>(x, ipw, xc_b, z_b);
  k_conv  <<<1536, 256, 0, stream>>>(xc_b, cw, cb, u_b);
  k_proj  <<<1024, 128, 0, stream>>>(u_b, xpw, dts_b, Bs_b, Cs_b);
  k_scanA <<<1024, 384, 0, stream>>>(u_b, dts_b, Bs_b, dtw, dtb, alg, S_b, sumd_b);
  k_scanB <<<96, 256, 0, stream>>>(S_b, sumd_b, alg, hin_b);
  k_scanC <<<1024, 384, 0, stream>>>(u_b, dts_b, Bs_b, Cs_b, dtw, dtb, alg, hin_b, ys_b);
  k_out   <<<256, 256, 0, stream>>>(ys_b, u_b, dsg, z_b, nw, nb, wo, out);
}

// Round 5
// 241.104 us; speedup vs baseline: 1.4873x; 1.1359x over previous
//
#include <hip/hip_runtime.h>
#include <math.h>

// MS2D (VMamba SS2D) pipeline for MI355X.
// B=4, H=W=64, L=4096, DM=DI=96, N=16 states, K=4 directions, DTR=6.
// Chunked selective scan: NCH=128 chunks of LCH=32 steps.
// Scan blocks: 384 threads = 2 chunks x 96 d x 2 n-halves; all chunk data
// bulk-staged into LDS, delta/exp precomputed out of the serial loop.

#define LQ 4096
#define NCH 128  // chunks
#define LCH 32   // chunk length

__device__ __forceinline__ float sigmoid_f(float x){ return 1.0f/(1.0f + __expf(-x)); }
__device__ __forceinline__ float silu_f(float x){ return x * sigmoid_f(x); }
__device__ __forceinline__ float softplus_f(float x){ return (x > 20.0f) ? x : __logf(1.0f + __expf(x)); }

// scan-order index i -> spatial position p = h*64+w, for direction k.
__device__ __forceinline__ int pos_of(int k, int i){
  switch(k & 3){
    case 0: return i;                                   // h,w raster
    case 1: return ((i & 63) << 6) | (i >> 6);          // w,h raster (transposed)
    case 2: return LQ - 1 - i;                          // reversed h,w
    default: { int j = LQ - 1 - i; return ((j & 63) << 6) | (j >> 6); }
  }
}

// half-powchain: e[j] = r^(j+1) for j<8, scaled by r^8 if nh==1.
__device__ __forceinline__ void pow8(float r, int nh, float* e){
  e[0]=r;
  e[1]=r*r;
  e[2]=e[1]*r;
  e[3]=e[1]*e[1];
  e[4]=e[3]*r;
  e[5]=e[3]*e[1];
  e[6]=e[3]*e[2];
  e[7]=e[3]*e[3];
  float m = nh ? e[7] : 1.0f;
  #pragma unroll
  for (int j=0;j<8;j++) e[j] *= m;
}

// ---------------- K1: in_proj GEMM (col-split): 512 blocks ----------------
__global__ __launch_bounds__(256) void k_inproj(const float* __restrict__ x,
                                                const float* __restrict__ wproj,
                                                float* __restrict__ xc,
                                                float* __restrict__ zb){
  __shared__ float a_s[64*97];     // 64 rows x 96 (+1 pad)
  __shared__ float w_s[96*97];     // 96 out-cols x 96 (+1 pad)
  const int t = threadIdx.x;
  const int row0 = (blockIdx.x >> 1) * 64;
  const int ch = blockIdx.x & 1;   // 0 -> xc cols, 1 -> z cols
  for (int e = t*4; e < 64*96; e += 1024){
    float4 v = *(const float4*)(x + (size_t)row0*96 + e);
    int r = e/96, c = e%96;
    float* p = a_s + r*97 + c;
    p[0]=v.x; p[1]=v.y; p[2]=v.z; p[3]=v.w;
  }
  for (int e = t*4; e < 96*96; e += 1024){
    float4 v = *(const float4*)(wproj + (size_t)ch*96*96 + e);
    int r = e/96, c = e%96;
    float* p = w_s + r*97 + c;
    p[0]=v.x; p[1]=v.y; p[2]=v.z; p[3]=v.w;
  }
  __syncthreads();
  const int tr = t >> 5, tc = t & 31;   // micro-tile: 8 rows x 3 cols
  float acc[8][3];
  #pragma unroll
  for (int i=0;i<8;i++){
    #pragma unroll
    for (int j=0;j<3;j++) acc[i][j]=0.f;
  }
  for (int kk=0; kk<96; kk++){
    float a[8], b[3];
    #pragma unroll
    for (int i=0;i<8;i++) a[i] = a_s[(tr*8+i)*97+kk];
    #pragma unroll
    for (int j=0;j<3;j++) b[j] = w_s[(tc*3+j)*97+kk];
    #pragma unroll
    for (int i=0;i<8;i++){
      #pragma unroll
      for (int j=0;j<3;j++) acc[i][j] += a[i]*b[j];
    }
  }
  float* dst = ch ? zb : xc;
  #pragma unroll
  for (int i=0;i<8;i++){
    int row = row0 + tr*8 + i;
    #pragma unroll
    for (int j=0;j<3;j++) dst[(size_t)row*96 + tc*3 + j] = acc[i][j];
  }
}

// ---------------- K2: depthwise 3x3 conv (SAME) + bias + SiLU, float4 ------
__global__ __launch_bounds__(256) void k_conv(const float* __restrict__ xc,
                                              const float* __restrict__ cw,
                                              const float* __restrict__ cb,
                                              float* __restrict__ u){
  int e = blockIdx.x*256 + threadIdx.x;      // < 4*4096*24
  int d0 = (e % 24) * 4;
  int p = e / 24;                            // GLOBAL row: b*4096 + spatial
  int w = p & 63, h = (p >> 6) & 63, b = p >> 12;
  float cwv[4][9];
  #pragma unroll
  for (int q=0;q<4;q++){
    #pragma unroll
    for (int tp=0;tp<9;tp++) cwv[q][tp] = cw[(d0+q)*9+tp];
  }
  float4 acc = make_float4(cb[d0], cb[d0+1], cb[d0+2], cb[d0+3]);
  #pragma unroll
  for (int kh=0; kh<3; kh++){
    int hh = h + kh - 1;
    if (hh < 0 || hh > 63) continue;
    #pragma unroll
    for (int kw=0; kw<3; kw++){
      int ww = w + kw - 1;
      if (ww < 0 || ww > 63) continue;
      float4 v = *(const float4*)(xc + ((size_t)((b<<12) + (hh<<6) + ww))*96 + d0);
      int tp = kh*3+kw;
      acc.x += v.x*cwv[0][tp]; acc.y += v.y*cwv[1][tp];
      acc.z += v.z*cwv[2][tp]; acc.w += v.w*cwv[3][tp];
    }
  }
  float4 o = make_float4(silu_f(acc.x), silu_f(acc.y), silu_f(acc.z), silu_f(acc.w));
  *(float4*)(u + (size_t)p*96 + d0) = o;   // p already includes batch offset
}

// ---------------- K3: x_proj: per (b,k,ptile): 38x96 x 64pos -> dt/B/C -----
__global__ __launch_bounds__(128) void k_proj(const float* __restrict__ u,
                                              const float* __restrict__ xpw,
                                              float* __restrict__ dts,
                                              float* __restrict__ Bsb,
                                              float* __restrict__ Csb){
  __shared__ float u_s[64*97];   // 64 positions x 96
  __shared__ float w_s[40*97];   // 38 (+2 zero pad) x 96
  const int t = threadIdx.x;
  const int blk = blockIdx.x;             // B*K*64 = 1024
  const int pt = blk & 63, k = (blk >> 6) & 3, b = blk >> 8;
  const int p0 = pt * 64;
  for (int e = t*4; e < 64*96; e += 512){
    int pp = e/96, c = e%96;
    float4 v = *(const float4*)(u + ((size_t)((b<<12) + p0 + pp))*96 + c);
    float* p = u_s + pp*97 + c;
    p[0]=v.x; p[1]=v.y; p[2]=v.z; p[3]=v.w;
  }
  for (int e = t*4; e < 40*96; e += 512){
    int r = e/96, c = e%96;
    float4 v = (r < 38) ? *(const float4*)(xpw + (k*38+r)*96 + c)
                        : make_float4(0,0,0,0);
    float* p = w_s + r*97 + c;
    p[0]=v.x; p[1]=v.y; p[2]=v.z; p[3]=v.w;
  }
  __syncthreads();
  const int posg = t & 15, cg = t >> 4;    // micro-tile 4 pos x 5 c
  float acc[4][5];
  #pragma unroll
  for (int i=0;i<4;i++){
    #pragma unroll
    for (int j=0;j<5;j++) acc[i][j]=0.f;
  }
  for (int dd=0; dd<96; dd++){
    float uu[4], wv[5];
    #pragma unroll
    for (int i=0;i<4;i++) uu[i] = u_s[(posg*4+i)*97+dd];
    #pragma unroll
    for (int j=0;j<5;j++) wv[j] = w_s[(cg*5+j)*97+dd];
    #pragma unroll
    for (int i=0;i<4;i++){
      #pragma unroll
      for (int j=0;j<5;j++) acc[i][j] += uu[i]*wv[j];
    }
  }
  #pragma unroll
  for (int i=0;i<4;i++){
    int p = p0 + posg*4 + i;
    int base = ((b*4+k)<<12) + p;
    #pragma unroll
    for (int j=0;j<5;j++){
      int c = cg*5 + j;
      float v = acc[i][j];
      if (c < 6)       dts[(size_t)base*6 + c] = v;
      else if (c < 22) Bsb[(size_t)base*16 + (c-6)] = v;
      else if (c < 38) Csb[(size_t)base*16 + (c-22)] = v;
    }
  }
}

// ---------------- K4: scan phase A (LDS-staged) ----------------------------
__global__ __launch_bounds__(384) void k_scanA(const float* __restrict__ u,
                                               const float* __restrict__ dts,
                                               const float* __restrict__ Bsb,
                                               const float* __restrict__ dtw_g,
                                               const float* __restrict__ dtb_g,
                                               const float* __restrict__ Alogs,
                                               float* __restrict__ S,
                                               float* __restrict__ sumd){
  __shared__ float du_s[64*96];   // staged u, overwritten with delta*u
  __shared__ float r_s[64*96];    // exp(-delta)
  __shared__ float dt_s[64*8];    // 6 used, pad 8
  __shared__ float B_s[64*16];
  __shared__ float sd_part[4*96];
  const int t = threadIdx.x;
  const int blk = blockIdx.x;              // 16 bk x 64
  const int bk = blk >> 6;
  const int k = bk & 3, b = bk >> 2;
  const int chunk0 = (blk & 63) << 1;
  // ---- stage: u (64 rows x 96), dt (64 x 6), B (64 x 16) ----
  for (int e = t*4; e < 64*96; e += 1536){
    int row = e/96, c = e%96;
    int p = pos_of(k, (chunk0 + (row>>5))*LCH + (row&31));
    float4 v = *(const float4*)(u + ((size_t)((b<<12)+p))*96 + c);
    float* dst = du_s + row*96 + c;
    dst[0]=v.x; dst[1]=v.y; dst[2]=v.z; dst[3]=v.w;
  }
  {
    int row = t/6, j = t - row*6;          // 384 = 64*6 exactly
    int p = pos_of(k, (chunk0 + (row>>5))*LCH + (row&31));
    dt_s[row*8+j] = dts[((size_t)((bk<<12)+p))*6 + j];
  }
  if (t < 256){
    int row = t>>2, q = t&3;
    int p = pos_of(k, (chunk0 + (row>>5))*LCH + (row&31));
    float4 v = *(const float4*)(Bsb + ((size_t)((bk<<12)+p))*16 + q*4);
    *(float4*)(B_s + row*16 + q*4) = v;
  }
  __syncthreads();
  // ---- prepass: delta -> du, r; partial sumd ----
  {
    const int d = t % 96, g = t / 96;      // g: 0..3
    const int c2 = g >> 1, il0 = (g & 1) * 16;
    float dtwv[6];
    #pragma unroll
    for (int r=0;r<6;r++) dtwv[r] = dtw_g[(k*96+d)*6+r];
    const float bias = dtb_g[k*96+d];
    float sd = 0.f;
    #pragma unroll 4
    for (int il = il0; il < il0+16; il++){
      int row = c2*32 + il;
      const float* dr = dt_s + row*8;
      float accd = bias + dr[0]*dtwv[0] + dr[1]*dtwv[1] + dr[2]*dtwv[2]
                        + dr[3]*dtwv[3] + dr[4]*dtwv[4] + dr[5]*dtwv[5];
      float delta = softplus_f(accd);
      sd += delta;
      int idx = row*96 + d;
      du_s[idx] = delta * du_s[idx];
      r_s[idx] = __expf(-delta);
    }
    sd_part[g*96 + d] = sd;
  }
  __syncthreads();
  // ---- scan ----
  const int c2 = t / 192;
  const int lane = t & 63;
  const int wv3 = (t % 192) >> 6;
  const int nh = (lane >> 5) & 1;
  const int d = wv3*32 + (lane & 31);
  float An[8];
  bool fast = true;
  #pragma unroll
  for (int j=0;j<8;j++){
    int n = nh*8 + j;
    An[j] = -__expf(Alogs[(k*96+d)*16+n]);
    fast = fast && (fabsf(An[j] + (float)(n+1)) < 1e-3f*(float)(n+1));
  }
  int wfast = __all(fast ? 1 : 0);
  float h[8];
  #pragma unroll
  for (int n=0;n<8;n++) h[n]=0.f;
  const float* dup = du_s + c2*32*96 + d;
  const float* rp  = r_s  + c2*32*96 + d;
  const float* Bb  = B_s + c2*32*16 + nh*8;
  if (wfast){
    #pragma unroll 4
    for (int il=0; il<LCH; il++){
      float r = rp[il*96];
      float du = dup[il*96];
      const float4* Bp = (const float4*)(Bb + il*16);
      float4 b0 = Bp[0], b1 = Bp[1];
      float Bv[8] = {b0.x,b0.y,b0.z,b0.w, b1.x,b1.y,b1.z,b1.w};
      float e[8];
      pow8(r, nh, e);
      #pragma unroll
      for (int n=0;n<8;n++) h[n] = h[n]*e[n] + du*Bv[n];
    }
  } else {
    #pragma unroll 2
    for (int il=0; il<LCH; il++){
      float r = rp[il*96];
      float delta = -__logf(r);
      float du = dup[il*96];
      const float4* Bp = (const float4*)(Bb + il*16);
      float4 b0 = Bp[0], b1 = Bp[1];
      float Bv[8] = {b0.x,b0.y,b0.z,b0.w, b1.x,b1.y,b1.z,b1.w};
      float e[8];
      #pragma unroll
      for (int n=0;n<8;n++) e[n] = __expf(delta*An[n]);
      #pragma unroll
      for (int n=0;n<8;n++) h[n] = h[n]*e[n] + du*Bv[n];
    }
  }
  const int sb = (bk*NCH + chunk0 + c2)*96 + d;
  float4* Sp = (float4*)(S + (size_t)sb*16 + nh*8);
  Sp[0] = make_float4(h[0],h[1],h[2],h[3]);
  Sp[1] = make_float4(h[4],h[5],h[6],h[7]);
  if (nh == 0) sumd[sb] = sd_part[(c2*2)*96 + d] + sd_part[(c2*2+1)*96 + d];
}

// ---------------- K5: scan phase B: stitch chunk states --------------------
__global__ __launch_bounds__(256) void k_scanB(const float* __restrict__ S,
                                               const float* __restrict__ sumd,
                                               const float* __restrict__ Alogs,
                                               float* __restrict__ hinit){
  const int t = blockIdx.x*256 + threadIdx.x;  // < 16*96*16 = 24576
  const int n = t & 15;
  const int d = (t >> 4) % 96;
  const int bk = t / 1536;
  const int k = bk & 3;
  const float An = -__expf(Alogs[(k*96+d)*16+n]);
  float h = 0.f;
  for (int c=0;c<NCH;c++){
    const int sb = (bk*NCH + c)*96 + d;
    hinit[(size_t)sb*16+n] = h;
    float P = __expf(An * sumd[sb]);
    h = h*P + S[(size_t)sb*16+n];
  }
}

// ---------------- K6: scan phase C (LDS-staged), emit y --------------------
__global__ __launch_bounds__(384) void k_scanC(const float* __restrict__ u,
                                               const float* __restrict__ dts,
                                               const float* __restrict__ Bsb,
                                               const float* __restrict__ Csb,
                                               const float* __restrict__ dtw_g,
                                               const float* __restrict__ dtb_g,
                                               const float* __restrict__ Alogs,
                                               const float* __restrict__ hinit,
                                               float* __restrict__ ys){
  __shared__ float du_s[64*96];
  __shared__ float r_s[64*96];
  __shared__ float dt_s[64*8];
  __shared__ float B_s[64*16];
  __shared__ float C_s[64*16];
  const int t = threadIdx.x;
  const int blk = blockIdx.x;
  const int bk = blk >> 6;
  const int k = bk & 3, b = bk >> 2;
  const int chunk0 = (blk & 63) << 1;
  for (int e = t*4; e < 64*96; e += 1536){
    int row = e/96, c = e%96;
    int p = pos_of(k, (chunk0 + (row>>5))*LCH + (row&31));
    float4 v = *(const float4*)(u + ((size_t)((b<<12)+p))*96 + c);
    float* dst = du_s + row*96 + c;
    dst[0]=v.x; dst[1]=v.y; dst[2]=v.z; dst[3]=v.w;
  }
  {
    int row = t/6, j = t - row*6;
    int p = pos_of(k, (chunk0 + (row>>5))*LCH + (row&31));
    dt_s[row*8+j] = dts[((size_t)((bk<<12)+p))*6 + j];
  }
  if (t < 256){
    int row = t>>2, q = t&3;
    int p = pos_of(k, (chunk0 + (row>>5))*LCH + (row&31));
    float4 v = *(const float4*)(Bsb + ((size_t)((bk<<12)+p))*16 + q*4);
    *(float4*)(B_s + row*16 + q*4) = v;
    float4 w = *(const float4*)(Csb + ((size_t)((bk<<12)+p))*16 + q*4);
    *(float4*)(C_s + row*16 + q*4) = w;
  }
  __syncthreads();
  {
    const int d = t % 96, g = t / 96;
    const int c2 = g >> 1, il0 = (g & 1) * 16;
    float dtwv[6];
    #pragma unroll
    for (int r=0;r<6;r++) dtwv[r] = dtw_g[(k*96+d)*6+r];
    const float bias = dtb_g[k*96+d];
    #pragma unroll 4
    for (int il = il0; il < il0+16; il++){
      int row = c2*32 + il;
      const float* dr = dt_s + row*8;
      float accd = bias + dr[0]*dtwv[0] + dr[1]*dtwv[1] + dr[2]*dtwv[2]
                        + dr[3]*dtwv[3] + dr[4]*dtwv[4] + dr[5]*dtwv[5];
      float delta = softplus_f(accd);
      int idx = row*96 + d;
      du_s[idx] = delta * du_s[idx];
      r_s[idx] = __expf(-delta);
    }
  }
  __syncthreads();
  const int c2 = t / 192;
  const int lane = t & 63;
  const int wv3 = (t % 192) >> 6;
  const int nh = (lane >> 5) & 1;
  const int d = wv3*32 + (lane & 31);
  float An[8];
  bool fast = true;
  #pragma unroll
  for (int j=0;j<8;j++){
    int n = nh*8 + j;
    An[j] = -__expf(Alogs[(k*96+d)*16+n]);
    fast = fast && (fabsf(An[j] + (float)(n+1)) < 1e-3f*(float)(n+1));
  }
  int wfast = __all(fast ? 1 : 0);
  const int chunk = chunk0 + c2;
  const int i0 = chunk*LCH;
  const int pb = pos_of(k, i0);
  const int pstep = pos_of(k, i0+1) - pb;
  float* yp = ys + ((size_t)((bk<<12)+pb))*96 + d;
  const long ystep = (long)pstep*96;
  float h[8];
  const int sb = (bk*NCH + chunk)*96 + d;
  const float4* Hp = (const float4*)(hinit + (size_t)sb*16 + nh*8);
  {
    float4 h0=Hp[0], h1=Hp[1];
    h[0]=h0.x;h[1]=h0.y;h[2]=h0.z;h[3]=h0.w;
    h[4]=h1.x;h[5]=h1.y;h[6]=h1.z;h[7]=h1.w;
  }
  const float* dup = du_s + c2*32*96 + d;
  const float* rp  = r_s  + c2*32*96 + d;
  const float* Bb  = B_s + c2*32*16 + nh*8;
  const float* Cb  = C_s + c2*32*16 + nh*8;
  if (wfast){
    #pragma unroll 4
    for (int il=0; il<LCH; il++){
      float r = rp[il*96];
      float du = dup[il*96];
      const float4* Bp = (const float4*)(Bb + il*16);
      const float4* Cp = (const float4*)(Cb + il*16);
      float4 b0 = Bp[0], b1 = Bp[1];
      float4 c0 = Cp[0], c1 = Cp[1];
      float Bv[8] = {b0.x,b0.y,b0.z,b0.w, b1.x,b1.y,b1.z,b1.w};
      float Cv[8] = {c0.x,c0.y,c0.z,c0.w, c1.x,c1.y,c1.z,c1.w};
      float e[8];
      pow8(r, nh, e);
      float y8 = 0.f;
      #pragma unroll
      for (int n=0;n<8;n++){
        h[n] = h[n]*e[n] + du*Bv[n];
        y8 += h[n]*Cv[n];
      }
      float y = y8 + __shfl_xor(y8, 32, 64);
      if (nh == 0) yp[il*ystep] = y;
    }
  } else {
    #pragma unroll 2
    for (int il=0; il<LCH; il++){
      float r = rp[il*96];
      float delta = -__logf(r);
      float du = dup[il*96];
      const float4* Bp = (const float4*)(Bb + il*16);
      const float4* Cp = (const float4*)(Cb + il*16);
      float4 b0 = Bp[0], b1 = Bp[1];
      float4 c0 = Cp[0], c1 = Cp[1];
      float Bv[8] = {b0.x,b0.y,b0.z,b0.w, b1.x,b1.y,b1.z,b1.w};
      float Cv[8] = {c0.x,c0.y,c0.z,c0.w, c1.x,c1.y,c1.z,c1.w};
      float e[8];
      #pragma unroll
      for (int n=0;n<8;n++) e[n] = __expf(delta*An[n]);
      float y8 = 0.f;
      #pragma unroll
      for (int n=0;n<8;n++){
        h[n] = h[n]*e[n] + du*Bv[n];
        y8 += h[n]*Cv[n];
      }
      float y = y8 + __shfl_xor(y8, 32, 64);
      if (nh == 0) yp[il*ystep] = y;
    }
  }
}

// ---------------- K7: sum 4 dirs + D*u + LN + z-gate + out_proj (split) ----
__global__ __launch_bounds__(256) void k_out(const float* __restrict__ ys,
                                             const float* __restrict__ ubuf,
                                             const float* __restrict__ Dsg,
                                             const float* __restrict__ zbuf,
                                             const float* __restrict__ nw,
                                             const float* __restrict__ nb,
                                             const float* __restrict__ wout,
                                             float* __restrict__ out){
  __shared__ float w_s[96*97];
  __shared__ float g_s[32*97];
  const int t = threadIdx.x;
  const int b = blockIdx.x >> 7;      // 512 blocks: b in 0..3, 128 pos tiles
  const int pt = blockIdx.x & 127;
  const int p0 = pt * 32;
  for (int e=t*4; e<96*96; e+=1024){
    float4 v = *(const float4*)(wout+e);
    int r=e/96, c=e%96;
    float* p = w_s + r*97 + c;
    p[0]=v.x; p[1]=v.y; p[2]=v.z; p[3]=v.w;
  }
  // phase 1: LN stats. thread -> (pos = t>>3, lane8 = t&7), 12 d each
  const int pos = t >> 3, lane8 = t & 7, d0 = lane8*12;
  const int p = p0 + pos;
  float yv[12];
  float s1=0.f, s2=0.f;
  #pragma unroll
  for (int i=0;i<12;i+=4){
    float4 a = make_float4(0,0,0,0);
    #pragma unroll
    for (int kk=0;kk<4;kk++){
      float4 v = *(const float4*)(ys + ((size_t)(((b*4+kk)<<12) + p))*96 + d0 + i);
      a.x+=v.x; a.y+=v.y; a.z+=v.z; a.w+=v.w;
    }
    float4 uv = *(const float4*)(ubuf + ((size_t)((b<<12)+p))*96 + d0 + i);
    #pragma unroll
    for (int q=0;q<4;q++){
      int dd = d0+i+q;
      float sD = Dsg[dd] + Dsg[96+dd] + Dsg[192+dd] + Dsg[288+dd];
      float uq = (q==0)?uv.x:(q==1)?uv.y:(q==2)?uv.z:uv.w;
      float* aq = (q==0)?&a.x:(q==1)?&a.y:(q==2)?&a.z:&a.w;
      *aq += sD * uq;
    }
    yv[i]=a.x; yv[i+1]=a.y; yv[i+2]=a.z; yv[i+3]=a.w;
    s1 += a.x+a.y+a.z+a.w;
    s2 += a.x*a.x + a.y*a.y + a.z*a.z + a.w*a.w;
  }
  // 8-lane reduction within wave (groups of 8 aligned lanes)
  #pragma unroll
  for (int m=1; m<8; m<<=1){
    s1 += __shfl_xor(s1, m, 64);
    s2 += __shfl_xor(s2, m, 64);
  }
  const float mu = s1 * (1.0f/96.0f);
  const float var = s2 * (1.0f/96.0f) - mu*mu;
  const float rstd = rsqrtf(var + 1e-5f);
  #pragma unroll
  for (int i=0;i<12;i+=4){
    float4 zv = *(const float4*)(zbuf + ((size_t)((b<<12)+p))*96 + d0 + i);
    float zz[4] = {zv.x,zv.y,zv.z,zv.w};
    #pragma unroll
    for (int q=0;q<4;q++){
      int d = d0+i+q;
      float yn = (yv[i+q]-mu)*rstd*nw[d] + nb[d];
      g_s[pos*97 + d] = yn * silu_f(zz[q]);
    }
  }
  __syncthreads();
  // phase 2: out GEMM. thread -> (posg = t>>5: 4 pos, mg = t&31: 3 m)
  const int posg = t >> 5, mg = t & 31;
  float acc[4][3];
  #pragma unroll
  for (int i=0;i<4;i++){
    #pragma unroll
    for (int j=0;j<3;j++) acc[i][j]=0.f;
  }
  for (int dd=0; dd<96; dd++){
    float g4[4], w3[3];
    #pragma unroll
    for (int i=0;i<4;i++) g4[i] = g_s[(posg*4+i)*97+dd];
    #pragma unroll
    for (int j=0;j<3;j++) w3[j] = w_s[(mg*3+j)*97+dd];
    #pragma unroll
    for (int i=0;i<4;i++){
      #pragma unroll
      for (int j=0;j<3;j++) acc[i][j] += g4[i]*w3[j];
    }
  }
  #pragma unroll
  for (int i=0;i<4;i++){
    int prow = p0 + posg*4 + i;
    #pragma unroll
    for (int j=0;j<3;j++){
      out[((size_t)((b<<12)+prow))*96 + mg*3 + j] = acc[i][j];
    }
  }
}

extern "C" void kernel_launch(void* const* d_in, const int* in_sizes, int n_in,
                              void* d_out, int out_size, void* d_ws, size_t ws_size,
                              hipStream_t stream) {
  (void)in_sizes; (void)n_in; (void)out_size; (void)ws_size;
  const float* x   = (const float*)d_in[0];
  const float* ipw = (const float*)d_in[1];
  const float* cw  = (const float*)d_in[2];
  const float* cb  = (const float*)d_in[3];
  const float* xpw = (const float*)d_in[4];
  const float* dtw = (const float*)d_in[5];
  const float* dtb = (const float*)d_in[6];
  const float* alg = (const float*)d_in[7];
  const float* dsg = (const float*)d_in[8];
  const float* nw  = (const float*)d_in[9];
  const float* nb  = (const float*)d_in[10];
  const float* wo  = (const float*)d_in[11];
  float* out = (float*)d_out;

  // workspace layout (floats), total = 15,073,280 floats = 60.3 MB
  // ys region (6.29M) is time-shared: [xc 1.57M | S 3.15M | sumd 0.20M | 1.37M]
  float* w = (float*)d_ws;
  size_t off = 0;
  float* z_b    = w + off; off += 1572864;             // (B,L,96) z gate
  float* u_b    = w + off; off += 1572864;             // (B,L,96) conv+silu
  float* dts_b  = w + off; off += 393216;              // (B,K,L,6)
  float* Bs_b   = w + off; off += 1048576;             // (B,K,L,16)
  float* Cs_b   = w + off; off += 1048576;             // (B,K,L,16)
  float* hin_b  = w + off; off += 3145728;             // (B*K,NCH,96,16)
  float* ys_b   = w + off; off += 6291456;             // (B*K,L,96)
  float* xc_b   = ys_b;                                // alias
  float* S_b    = ys_b + 1572864;                      // alias
  float* sumd_b = ys_b + 1572864 + 3145728;            // alias

  k_inproj<<<512, 256, 0, stream>>>(x, ipw, xc_b, z_b);
  k_conv  <<<1536, 256, 0, stream>>>(xc_b, cw, cb, u_b);
  k_proj  <<<1024, 128, 0, stream>>>(u_b, xpw, dts_b, Bs_b, Cs_b);
  k_scanA <<<1024, 384, 0, stream>>>(u_b, dts_b, Bs_b, dtw, dtb, alg, S_b, sumd_b);
  k_scanB <<<96, 256, 0, stream>>>(S_b, sumd_b, alg, hin_b);
  k_scanC <<<1024, 384, 0, stream>>>(u_b, dts_b, Bs_b, Cs_b, dtw, dtb, alg, hin_b, ys_b);
  k_out   <<<512, 256, 0, stream>>>(ys_b, u_b, dsg, z_b, nw, nb, wo, out);
}